// Round 2
// baseline (1179.949 us; speedup 1.0000x reference)
//
#include <hip/hip_runtime.h>
#include <math.h>

#define DIMK 4096
#define NEXP 256
#define BM   64
#define BK   16
#define NGRP 8
#define GSZ  32
#define TOPKG 4
#define TOPKE 8

// One block: 64 tokens x 256 experts, K = 4096.
// GEMM in fp64 accumulation (fp32 inputs -> exact products in f64) so that
// expert ranking matches the fp32/fp64 numpy reference bit-for-bit in practice.
// Routing (group top-2 sum -> top-4 groups -> top-8 experts, stable-argsort
// tie semantics) fused in the same block via an LDS score buffer.
__global__ __launch_bounds__(256, 1) void moe_gate_kernel(
    const float* __restrict__ x, const float* __restrict__ wgt,
    const float* __restrict__ bias, float* __restrict__ outw,
    float* __restrict__ outi) {
  // LDS union: [GEMM staging: lw 32768 B + lx 8704 B] vs [scores: 64*257*8 B]
  __shared__ __align__(16) unsigned char smem[64 * 257 * 8];  // 131584 B
  float* lw = (float*)smem;            // [2][BK][NEXP]
  float* lx = (float*)(smem + 32768);  // [2][BK][68]
  double* sc = (double*)smem;          // [64][257]

  const int tid = threadIdx.x;
  const long bm0 = (long)blockIdx.x * BM;
  const int rg = tid >> 5;        // 0..7 row-group (8 rows each)
  const int cg = tid & 31;        // 0..31 col-group
  const int sxr = tid >> 2;       // 0..63 staging token row
  const int sxj = (tid & 3) << 2; // staging k offset 0,4,8,12

  const float* xrow = x + (bm0 + sxr) * (long)DIMK + sxj;
  const float* wrow = wgt + (long)tid * DIMK;

  double acc[8][8];
#pragma unroll
  for (int i = 0; i < 8; ++i)
#pragma unroll
    for (int j = 0; j < 8; ++j) acc[i][j] = 0.0;

#define LW(b, k, e) lw[((b)*BK + (k)) * NEXP + (e)]
#define LX(b, k, r) lx[((b)*BK + (k)) * 68 + (r)]

  // stage k-tile 0 into buffer 0
  {
    float4 xv = *(const float4*)(xrow);
#pragma unroll
    for (int c = 0; c < 4; ++c) LX(0, sxj + c, sxr) = ((const float*)&xv)[c];
#pragma unroll
    for (int jj = 0; jj < 4; ++jj) {
      float4 wv = *(const float4*)(wrow + jj * 4);
#pragma unroll
      for (int c = 0; c < 4; ++c) LW(0, jj * 4 + c, tid) = ((const float*)&wv)[c];
    }
  }
  __syncthreads();

  const int NT = DIMK / BK;  // 256 k-tiles
  for (int kt = 0; kt < NT; ++kt) {
    const int b = kt & 1;
    if (kt + 1 < NT) {
      const int k0 = (kt + 1) * BK;
      const int nb = b ^ 1;
      float4 xv = *(const float4*)(xrow + k0);
      float4 wv0 = *(const float4*)(wrow + k0);
      float4 wv1 = *(const float4*)(wrow + k0 + 4);
      float4 wv2 = *(const float4*)(wrow + k0 + 8);
      float4 wv3 = *(const float4*)(wrow + k0 + 12);
#pragma unroll
      for (int c = 0; c < 4; ++c) LX(nb, sxj + c, sxr) = ((const float*)&xv)[c];
#pragma unroll
      for (int c = 0; c < 4; ++c) LW(nb, 0 + c, tid) = ((const float*)&wv0)[c];
#pragma unroll
      for (int c = 0; c < 4; ++c) LW(nb, 4 + c, tid) = ((const float*)&wv1)[c];
#pragma unroll
      for (int c = 0; c < 4; ++c) LW(nb, 8 + c, tid) = ((const float*)&wv2)[c];
#pragma unroll
      for (int c = 0; c < 4; ++c) LW(nb, 12 + c, tid) = ((const float*)&wv3)[c];
    }
#pragma unroll
    for (int k = 0; k < BK; ++k) {
      float4 a0 = *(const float4*)(&LX(b, k, rg * 8));
      float4 a1 = *(const float4*)(&LX(b, k, rg * 8 + 4));
      double ad[8] = {(double)a0.x, (double)a0.y, (double)a0.z, (double)a0.w,
                      (double)a1.x, (double)a1.y, (double)a1.z, (double)a1.w};
      double bd[8];
#pragma unroll
      for (int j = 0; j < 4; ++j) {
        float2 bb = *(const float2*)(&LW(b, k, cg * 2 + 64 * j));
        bd[2 * j] = (double)bb.x;
        bd[2 * j + 1] = (double)bb.y;
      }
#pragma unroll
      for (int i = 0; i < 8; ++i)
#pragma unroll
        for (int j = 0; j < 8; ++j) acc[i][j] += ad[i] * bd[j];
    }
    __syncthreads();  // next buffer staged; current buffer free for overwrite
  }

  // ---- write biased scores (f64 sigmoid + bias) into LDS (aliases staging) ----
  double bc[8];
#pragma unroll
  for (int j = 0; j < 4; ++j) {
    bc[2 * j] = (double)bias[cg * 2 + 64 * j];
    bc[2 * j + 1] = (double)bias[cg * 2 + 64 * j + 1];
  }
#pragma unroll
  for (int i = 0; i < 8; ++i) {
    const int r = rg * 8 + i;
#pragma unroll
    for (int jq = 0; jq < 8; ++jq) {
      const int col = cg * 2 + 64 * (jq >> 1) + (jq & 1);
      double s = 1.0 / (1.0 + exp(-acc[i][jq]));  // original (sigmoid) score
      sc[r * 257 + col] = s + bc[jq];             // biased score for ranking
    }
  }
  __syncthreads();

  // ---- routing: one lane per token ----
  if (tid < BM) {
    double* row = sc + tid * 257;
    // group scores = sum of top-2 biased scores per group
    double gs[NGRP];
#pragma unroll
    for (int g = 0; g < NGRP; ++g) {
      double m1 = -1e300, m2 = -1e300;
      for (int e = 0; e < GSZ; ++e) {
        double v = row[g * GSZ + e];
        if (v > m1) { m2 = m1; m1 = v; }
        else if (v > m2) { m2 = v; }
      }
      gs[g] = m1 + m2;
    }
    // top-4 groups, stable-argsort-take-last semantics:
    // selected iff #{h: gs[h]>gs[g] || (gs[h]==gs[g] && h>g)} < 4
    unsigned msk = 0;
#pragma unroll
    for (int g = 0; g < NGRP; ++g) {
      int cnt = 0;
#pragma unroll
      for (int h = 0; h < NGRP; ++h)
        cnt += ((gs[h] > gs[g]) || (gs[h] == gs[g] && h > g)) ? 1 : 0;
      if (cnt < TOPKG) msk |= (1u << g);
    }
    int g0 = __ffs(msk) - 1; msk &= msk - 1;
    int g1 = __ffs(msk) - 1; msk &= msk - 1;
    int g2 = __ffs(msk) - 1; msk &= msk - 1;
    int g3 = __ffs(msk) - 1;   // g0<g1<g2<g3 ascending

    double wv[TOPKE];
    float iv[TOPKE];
#pragma unroll
    for (int r8 = 0; r8 < TOPKE; ++r8) {
      double best = -1e300;
      int bi = 0;
      // scan groups in ascending expert order; '>=' => ties pick larger index,
      // matching stable ascending argsort take-last ordering
      {
        int gg = g0;
        for (int e = 0; e < GSZ; ++e) { double v = row[gg * GSZ + e]; if (v >= best) { best = v; bi = gg * GSZ + e; } }
        gg = g1;
        for (int e = 0; e < GSZ; ++e) { double v = row[gg * GSZ + e]; if (v >= best) { best = v; bi = gg * GSZ + e; } }
        gg = g2;
        for (int e = 0; e < GSZ; ++e) { double v = row[gg * GSZ + e]; if (v >= best) { best = v; bi = gg * GSZ + e; } }
        gg = g3;
        for (int e = 0; e < GSZ; ++e) { double v = row[gg * GSZ + e]; if (v >= best) { best = v; bi = gg * GSZ + e; } }
      }
      row[bi] = -1e300;                         // remove from next scans
      wv[7 - r8] = best - (double)bias[bi];     // original (pre-bias) score
      iv[7 - r8] = (float)bi;
    }
    double sum = 0.0;
#pragma unroll
    for (int p = 0; p < TOPKE; ++p) sum += wv[p];
    const double den = sum + 1e-20;
    const long trow = bm0 + tid;
#pragma unroll
    for (int p = 0; p < TOPKE; ++p) {
      outw[trow * 8 + p] = (float)(wv[p] / den * 2.5);
      outi[trow * 8 + p] = iv[p];
    }
  }
#undef LW
#undef LX
}

extern "C" void kernel_launch(void* const* d_in, const int* in_sizes, int n_in,
                              void* d_out, int out_size, void* d_ws, size_t ws_size,
                              hipStream_t stream) {
  const float* x = (const float*)d_in[0];
  const float* w = (const float*)d_in[1];
  const float* b = (const float*)d_in[2];
  const int ntok = in_sizes[0] / DIMK;  // 16384
  float* outw = (float*)d_out;
  float* outi = outw + (size_t)ntok * 8;
  dim3 grid(ntok / BM), block(256);
  hipLaunchKernelGGL(moe_gate_kernel, grid, block, 0, stream, x, w, b, outw, outi);
}

// Round 4
// 287.057 us; speedup vs baseline: 4.1105x; 4.1105x over previous
//
#include <hip/hip_runtime.h>
#include <math.h>

#define DIMK 4096
#define NEXP 256
#define BM   64
#define BK32 32
#define NT128 (DIMK / BK32)              // 128 k-tiles for mfma kernel
#define NGRP 8
#define GSZ  32
#define TOPKG 4
#define TOPKE 8
#define WS_NEED ((size_t)NT128 * 3 * 16 * 1024)   // 6,291,456 B of bf16 w-planes

typedef __bf16 bf16x8 __attribute__((ext_vector_type(8)));
typedef float f32x4 __attribute__((ext_vector_type(4)));

// ---- f32 -> 3x bf16 split: x ~= hi + mid + lo (residuals Sterbenz-exact) ----
__device__ __forceinline__ void decomp8(const float v[8], uint4& H, uint4& M, uint4& L) {
  union U { __bf16 b[8]; uint4 u; } h, m, l;
#pragma unroll
  for (int i = 0; i < 8; ++i) {
    float xv = v[i];
    __bf16 hb = (__bf16)xv;
    float r1 = xv - (float)hb;
    __bf16 mb = (__bf16)r1;
    float r2 = r1 - (float)mb;
    h.b[i] = hb; m.b[i] = mb; l.b[i] = (__bf16)r2;
  }
  H = h.u; M = m.u; L = l.u;
}

// ================= pre-kernel: decompose w into frag-native ws layout ========
// ws block for (tile t, plane p, expert-block eb) = 1024 B at ((t*3+p)*16+eb)*1024.
// Within a block: lane = ((k&31)>>3)*16 + (e&15) holds 8 bf16 = w[e][t*32+(lane>>4)*8+j].
__global__ __launch_bounds__(256) void w_split_kernel(const float* __restrict__ wgt,
                                                      unsigned char* __restrict__ ws) {
  const int g = blockIdx.x * 256 + threadIdx.x;   // 131072 threads
  const int e = g >> 9;                            // expert 0..255
  const int k0 = (g & 511) << 3;                   // k chunk of 8
  const int kt = k0 >> 5;
  const int chunk = (k0 & 31) >> 3;
  const int lane = chunk * 16 + (e & 15);
  const int eb = e >> 4;
  float v[8];
  float4 a = *(const float4*)(wgt + (long)e * DIMK + k0);
  float4 b = *(const float4*)(wgt + (long)e * DIMK + k0 + 4);
  v[0]=a.x; v[1]=a.y; v[2]=a.z; v[3]=a.w; v[4]=b.x; v[5]=b.y; v[6]=b.z; v[7]=b.w;
  uint4 H, M, L;
  decomp8(v, H, M, L);
  const long base = ((long)(kt * 3) * 16 + eb) * 1024 + lane * 16;
  *(uint4*)(ws + base)             = H;   // p=0
  *(uint4*)(ws + base + 16 * 1024) = M;   // p=1
  *(uint4*)(ws + base + 32 * 1024) = L;   // p=2
}

// ================= helpers for the mfma main kernel ==========================
__device__ __forceinline__ void mfma_group(const bf16x8 a[4], const bf16x8* b, f32x4 D[4][4]) {
#pragma unroll
  for (int rt = 0; rt < 4; ++rt)
#pragma unroll
    for (int ct = 0; ct < 4; ++ct)
      D[rt][ct] = __builtin_amdgcn_mfma_f32_16x16x32_bf16(a[rt], b[ct], D[rt][ct], 0, 0, 0);
}

__device__ __forceinline__ void groups_for_tile(const unsigned char* smem, int bufoff,
                                                int arow, const bf16x8* B, f32x4 D[4][4]) {
  bf16x8 ah[4], am[4], al[4];
#pragma unroll
  for (int rt = 0; rt < 4; ++rt) {
    ah[rt] = *(const bf16x8*)(smem + bufoff + 0 * 5120 + rt * 1280 + arow);
    am[rt] = *(const bf16x8*)(smem + bufoff + 1 * 5120 + rt * 1280 + arow);
    al[rt] = *(const bf16x8*)(smem + bufoff + 2 * 5120 + rt * 1280 + arow);
  }
  mfma_group(ah, B + 0, D);   // hi * w_hi
  mfma_group(am, B + 0, D);   // mid * w_hi
  mfma_group(al, B + 0, D);   // lo * w_hi
  mfma_group(ah, B + 4, D);   // hi * w_mid
  mfma_group(am, B + 4, D);   // mid * w_mid
  mfma_group(ah, B + 8, D);   // hi * w_lo
}

__device__ __forceinline__ void loadB(bf16x8* dst, const unsigned char* ws, int t,
                                      int wid, int lane) {
#pragma unroll
  for (int p = 0; p < 3; ++p)
#pragma unroll
    for (int ct = 0; ct < 4; ++ct)
      dst[p * 4 + ct] = *(const bf16x8*)(ws + ((long)((t * 3 + p) * 16 + wid * 4 + ct) << 10) + lane * 16);
}

// ================= main kernel: 64 tokens x 256 experts, bf16x3 MFMA =========
__global__ __launch_bounds__(256, 1) void moe_gate_mfma(
    const float* __restrict__ x, const unsigned char* __restrict__ ws,
    const float* __restrict__ bias, float* __restrict__ outw, float* __restrict__ outi) {
  // LDS: x-planes dbuf [2][3][64][40 bf16] = 30720 B at offset 0; later sc[64][257] f64.
  __shared__ __align__(16) unsigned char smem[64 * 257 * 8];  // 131584 B (proven size)
  double* sc = (double*)smem;

  const int tid = threadIdx.x;
  const int wid = tid >> 6;
  const int lane = tid & 63;
  const int l15 = lane & 15;
  const int hi16 = (lane >> 4) * 16;
  const long bm0 = (long)blockIdx.x * BM;

  const int token = tid >> 2;
  const int part = tid & 3;
  const float* xptr = x + (bm0 + token) * (long)DIMK + part * 8;
  const int arow = l15 * 80 + hi16;
  const int xw = token * 80 + part * 16;  // x ds_write byte offset within plane

  f32x4 D[4][4];
  double acc[4][4][4];
#pragma unroll
  for (int rt = 0; rt < 4; ++rt)
#pragma unroll
    for (int ct = 0; ct < 4; ++ct) {
      D[rt][ct] = (f32x4){0.f, 0.f, 0.f, 0.f};
#pragma unroll
      for (int r = 0; r < 4; ++r) acc[rt][ct][r] = 0.0;
    }

  bf16x8 bA[12], bB[12];

  // ---- prologue: b-frags for tile 0; x tile 0 -> LDS buf0 ----
  loadB(bA, ws, 0, wid, lane);
  {
    float v[8];
    float4 a0 = *(const float4*)(xptr);
    float4 a1 = *(const float4*)(xptr + 4);
    v[0]=a0.x; v[1]=a0.y; v[2]=a0.z; v[3]=a0.w; v[4]=a1.x; v[5]=a1.y; v[6]=a1.z; v[7]=a1.w;
    uint4 H, M, L; decomp8(v, H, M, L);
    *(uint4*)(smem + 0 * 5120 + xw) = H;
    *(uint4*)(smem + 1 * 5120 + xw) = M;
    *(uint4*)(smem + 2 * 5120 + xw) = L;
  }
  __syncthreads();

#pragma unroll 1
  for (int it = 0; it < NT128 / 2; ++it) {
    const int t1 = 2 * it + 1;
    // ---------- tile t0 = 2*it : LDS buf0, b-frags in bA ----------
    loadB(bB, ws, t1, wid, lane);                     // prefetch next tile's w-frags
    uint4 XH, XM, XL;
    {
      float v[8];
      float4 a0 = *(const float4*)(xptr + t1 * BK32);
      float4 a1 = *(const float4*)(xptr + t1 * BK32 + 4);
      v[0]=a0.x; v[1]=a0.y; v[2]=a0.z; v[3]=a0.w; v[4]=a1.x; v[5]=a1.y; v[6]=a1.z; v[7]=a1.w;
      decomp8(v, XH, XM, XL);
    }
    groups_for_tile(smem, 0, arow, bA, D);
    *(uint4*)(smem + 15360 + 0 * 5120 + xw) = XH;     // stage x(t1) -> buf1
    *(uint4*)(smem + 15360 + 1 * 5120 + xw) = XM;
    *(uint4*)(smem + 15360 + 2 * 5120 + xw) = XL;
    __syncthreads();
    // ---------- tile t1 : LDS buf1, b-frags in bB ----------
    const bool more = (it + 1 < NT128 / 2);
    if (more) {
      loadB(bA, ws, t1 + 1, wid, lane);
      float v[8];
      float4 a0 = *(const float4*)(xptr + (t1 + 1) * BK32);
      float4 a1 = *(const float4*)(xptr + (t1 + 1) * BK32 + 4);
      v[0]=a0.x; v[1]=a0.y; v[2]=a0.z; v[3]=a0.w; v[4]=a1.x; v[5]=a1.y; v[6]=a1.z; v[7]=a1.w;
      decomp8(v, XH, XM, XL);
    }
    groups_for_tile(smem, 15360, arow, bB, D);
    if (more) {
      *(uint4*)(smem + 0 * 5120 + xw) = XH;           // stage x(t1+1) -> buf0
      *(uint4*)(smem + 1 * 5120 + xw) = XM;
      *(uint4*)(smem + 2 * 5120 + xw) = XL;
    }
    if ((it & 1) == 1) {                              // flush f32 -> f64 every 128 k
#pragma unroll
      for (int rt = 0; rt < 4; ++rt)
#pragma unroll
        for (int ct = 0; ct < 4; ++ct) {
#pragma unroll
          for (int r = 0; r < 4; ++r) acc[rt][ct][r] += (double)D[rt][ct][r];
          D[rt][ct] = (f32x4){0.f, 0.f, 0.f, 0.f};
        }
    }
    __syncthreads();
  }

  // ---- epilogue: f64 sigmoid + bias -> sc (aliases staging LDS) ----
#pragma unroll
  for (int rt = 0; rt < 4; ++rt)
#pragma unroll
    for (int ct = 0; ct < 4; ++ct) {
      const int col = wid * 64 + ct * 16 + l15;
      const double bd = (double)bias[col];
#pragma unroll
      for (int r = 0; r < 4; ++r) {
        const int row = rt * 16 + (lane >> 4) * 4 + r;
        const double s = 1.0 / (1.0 + exp(-acc[rt][ct][r]));  // original score
        sc[row * 257 + col] = s + bd;                         // biased, for ranking
      }
    }
  __syncthreads();

  // ---- routing: one lane per token (verbatim from the round-2 PASSING kernel) ----
  if (tid < BM) {
    double* row = sc + tid * 257;
    double gs[NGRP];
#pragma unroll
    for (int g = 0; g < NGRP; ++g) {
      double m1 = -1e300, m2 = -1e300;
      for (int e = 0; e < GSZ; ++e) {
        double v = row[g * GSZ + e];
        if (v > m1) { m2 = m1; m1 = v; }
        else if (v > m2) { m2 = v; }
      }
      gs[g] = m1 + m2;
    }
    unsigned msk = 0;
#pragma unroll
    for (int g = 0; g < NGRP; ++g) {
      int cnt = 0;
#pragma unroll
      for (int h = 0; h < NGRP; ++h)
        cnt += ((gs[h] > gs[g]) || (gs[h] == gs[g] && h > g)) ? 1 : 0;
      if (cnt < TOPKG) msk |= (1u << g);
    }
    int g0 = __ffs(msk) - 1; msk &= msk - 1;
    int g1 = __ffs(msk) - 1; msk &= msk - 1;
    int g2 = __ffs(msk) - 1; msk &= msk - 1;
    int g3 = __ffs(msk) - 1;

    double wv[TOPKE];
    float iv[TOPKE];
#pragma unroll
    for (int r8 = 0; r8 < TOPKE; ++r8) {
      double best = -1e300;
      int bi = 0;
      {
        int gg = g0;
        for (int e = 0; e < GSZ; ++e) { double v = row[gg * GSZ + e]; if (v >= best) { best = v; bi = gg * GSZ + e; } }
        gg = g1;
        for (int e = 0; e < GSZ; ++e) { double v = row[gg * GSZ + e]; if (v >= best) { best = v; bi = gg * GSZ + e; } }
        gg = g2;
        for (int e = 0; e < GSZ; ++e) { double v = row[gg * GSZ + e]; if (v >= best) { best = v; bi = gg * GSZ + e; } }
        gg = g3;
        for (int e = 0; e < GSZ; ++e) { double v = row[gg * GSZ + e]; if (v >= best) { best = v; bi = gg * GSZ + e; } }
      }
      row[bi] = -1e300;
      wv[7 - r8] = best - (double)bias[bi];
      iv[7 - r8] = (float)bi;
    }
    double sum = 0.0;
#pragma unroll
    for (int p = 0; p < TOPKE; ++p) sum += wv[p];
    const double den = sum + 1e-20;
    const long trow = bm0 + tid;
#pragma unroll
    for (int p = 0; p < TOPKE; ++p) {
      outw[trow * 8 + p] = (float)(wv[p] / den * 2.5);
      outi[trow * 8 + p] = iv[p];
    }
  }
}

// ================= fallback: round-2 f64-VALU kernel (known-PASS) ============
#define BKF 16
#define LWSF 257
#define LXSF 68
__global__ __launch_bounds__(256, 1) void moe_gate_f64(
    const float* __restrict__ x, const float* __restrict__ wgt,
    const float* __restrict__ bias, float* __restrict__ outw,
    float* __restrict__ outi) {
  __shared__ __align__(16) unsigned char smem[64 * 257 * 8];
  float* lw = (float*)smem;
  float* lx = (float*)(smem + 32768);
  double* sc = (double*)smem;
  const int tid = threadIdx.x;
  const long bm0 = (long)blockIdx.x * BM;
  const int rg = tid >> 5;
  const int cg = tid & 31;
  const int sxr = tid >> 2;
  const int sxj = (tid & 3) << 2;
  const float* xrow = x + (bm0 + sxr) * (long)DIMK + sxj;
  const float* wrow = wgt + (long)tid * DIMK;
  double acc[8][8];
#pragma unroll
  for (int i = 0; i < 8; ++i)
#pragma unroll
    for (int j = 0; j < 8; ++j) acc[i][j] = 0.0;
#define LWF(b, k, e) lw[((b)*BKF + (k)) * NEXP + (e)]
#define LXF(b, k, r) lx[((b)*BKF + (k)) * LXSF + (r)]
  {
    float4 xv = *(const float4*)(xrow);
#pragma unroll
    for (int c = 0; c < 4; ++c) LXF(0, sxj + c, sxr) = ((const float*)&xv)[c];
#pragma unroll
    for (int jj = 0; jj < 4; ++jj) {
      float4 wv = *(const float4*)(wrow + jj * 4);
#pragma unroll
      for (int c = 0; c < 4; ++c) LWF(0, jj * 4 + c, tid) = ((const float*)&wv)[c];
    }
  }
  __syncthreads();
  const int NTF = DIMK / BKF;
  for (int kt = 0; kt < NTF; ++kt) {
    const int b = kt & 1;
    if (kt + 1 < NTF) {
      const int k0 = (kt + 1) * BKF;
      const int nb = b ^ 1;
      float4 xv = *(const float4*)(xrow + k0);
      float4 wv0 = *(const float4*)(wrow + k0);
      float4 wv1 = *(const float4*)(wrow + k0 + 4);
      float4 wv2 = *(const float4*)(wrow + k0 + 8);
      float4 wv3 = *(const float4*)(wrow + k0 + 12);
#pragma unroll
      for (int c = 0; c < 4; ++c) LXF(nb, sxj + c, sxr) = ((const float*)&xv)[c];
#pragma unroll
      for (int c = 0; c < 4; ++c) LWF(nb, 0 + c, tid) = ((const float*)&wv0)[c];
#pragma unroll
      for (int c = 0; c < 4; ++c) LWF(nb, 4 + c, tid) = ((const float*)&wv1)[c];
#pragma unroll
      for (int c = 0; c < 4; ++c) LWF(nb, 8 + c, tid) = ((const float*)&wv2)[c];
#pragma unroll
      for (int c = 0; c < 4; ++c) LWF(nb, 12 + c, tid) = ((const float*)&wv3)[c];
    }
#pragma unroll
    for (int k = 0; k < BKF; ++k) {
      float4 a0 = *(const float4*)(&LXF(b, k, rg * 8));
      float4 a1 = *(const float4*)(&LXF(b, k, rg * 8 + 4));
      double ad[8] = {(double)a0.x, (double)a0.y, (double)a0.z, (double)a0.w,
                      (double)a1.x, (double)a1.y, (double)a1.z, (double)a1.w};
      double bd[8];
#pragma unroll
      for (int j = 0; j < 4; ++j) {
        float2 bb = *(const float2*)(&LWF(b, k, cg * 2 + 64 * j));
        bd[2 * j] = (double)bb.x;
        bd[2 * j + 1] = (double)bb.y;
      }
#pragma unroll
      for (int i = 0; i < 8; ++i)
#pragma unroll
        for (int j = 0; j < 8; ++j) acc[i][j] += ad[i] * bd[j];
    }
    __syncthreads();
  }
  double bc[8];
#pragma unroll
  for (int j = 0; j < 4; ++j) {
    bc[2 * j] = (double)bias[cg * 2 + 64 * j];
    bc[2 * j + 1] = (double)bias[cg * 2 + 64 * j + 1];
  }
#pragma unroll
  for (int i = 0; i < 8; ++i) {
    const int r = rg * 8 + i;
#pragma unroll
    for (int jq = 0; jq < 8; ++jq) {
      const int col = cg * 2 + 64 * (jq >> 1) + (jq & 1);
      double s = 1.0 / (1.0 + exp(-acc[i][jq]));
      sc[r * 257 + col] = s + bc[jq];
    }
  }
  __syncthreads();
  if (tid < BM) {
    double* row = sc + tid * 257;
    double gs[NGRP];
#pragma unroll
    for (int g = 0; g < NGRP; ++g) {
      double m1 = -1e300, m2 = -1e300;
      for (int e = 0; e < GSZ; ++e) {
        double v = row[g * GSZ + e];
        if (v > m1) { m2 = m1; m1 = v; }
        else if (v > m2) { m2 = v; }
      }
      gs[g] = m1 + m2;
    }
    unsigned msk = 0;
#pragma unroll
    for (int g = 0; g < NGRP; ++g) {
      int cnt = 0;
#pragma unroll
      for (int h = 0; h < NGRP; ++h)
        cnt += ((gs[h] > gs[g]) || (gs[h] == gs[g] && h > g)) ? 1 : 0;
      if (cnt < TOPKG) msk |= (1u << g);
    }
    int g0 = __ffs(msk) - 1; msk &= msk - 1;
    int g1 = __ffs(msk) - 1; msk &= msk - 1;
    int g2 = __ffs(msk) - 1; msk &= msk - 1;
    int g3 = __ffs(msk) - 1;
    double wv[TOPKE];
    float iv[TOPKE];
#pragma unroll
    for (int r8 = 0; r8 < TOPKE; ++r8) {
      double best = -1e300;
      int bi = 0;
      {
        int gg = g0;
        for (int e = 0; e < GSZ; ++e) { double v = row[gg * GSZ + e]; if (v >= best) { best = v; bi = gg * GSZ + e; } }
        gg = g1;
        for (int e = 0; e < GSZ; ++e) { double v = row[gg * GSZ + e]; if (v >= best) { best = v; bi = gg * GSZ + e; } }
        gg = g2;
        for (int e = 0; e < GSZ; ++e) { double v = row[gg * GSZ + e]; if (v >= best) { best = v; bi = gg * GSZ + e; } }
        gg = g3;
        for (int e = 0; e < GSZ; ++e) { double v = row[gg * GSZ + e]; if (v >= best) { best = v; bi = gg * GSZ + e; } }
      }
      row[bi] = -1e300;
      wv[7 - r8] = best - (double)bias[bi];
      iv[7 - r8] = (float)bi;
    }
    double sum = 0.0;
#pragma unroll
    for (int p = 0; p < TOPKE; ++p) sum += wv[p];
    const double den = sum + 1e-20;
    const long trow = bm0 + tid;
#pragma unroll
    for (int p = 0; p < TOPKE; ++p) {
      outw[trow * 8 + p] = (float)(wv[p] / den * 2.5);
      outi[trow * 8 + p] = iv[p];
    }
  }
}

extern "C" void kernel_launch(void* const* d_in, const int* in_sizes, int n_in,
                              void* d_out, int out_size, void* d_ws, size_t ws_size,
                              hipStream_t stream) {
  const float* x = (const float*)d_in[0];
  const float* w = (const float*)d_in[1];
  const float* b = (const float*)d_in[2];
  const int ntok = in_sizes[0] / DIMK;  // 16384
  float* outw = (float*)d_out;
  float* outi = outw + (size_t)ntok * 8;
  if (ws_size >= WS_NEED) {
    hipLaunchKernelGGL(w_split_kernel, dim3(512), dim3(256), 0, stream,
                       w, (unsigned char*)d_ws);
    hipLaunchKernelGGL(moe_gate_mfma, dim3(ntok / BM), dim3(256), 0, stream,
                       x, (const unsigned char*)d_ws, b, outw, outi);
  } else {
    hipLaunchKernelGGL(moe_gate_f64, dim3(ntok / BM), dim3(256), 0, stream,
                       x, w, b, outw, outi);
  }
}

// Round 6
// 281.956 us; speedup vs baseline: 4.1849x; 1.0181x over previous
//
#include <hip/hip_runtime.h>
#include <math.h>

#define DIMK 4096
#define NEXP 256
#define BM   32
#define BK32 32
#define NT128 (DIMK / BK32)              // 128 k-tiles for mfma kernel
#define NGRP 8
#define GSZ  32
#define TOPKG 4
#define TOPKE 8
#define WS_NEED ((size_t)NT128 * 3 * 16 * 1024)   // 6,291,456 B of bf16 w-planes

// x-plane geometry (per buffer): 3 planes x 2048 B; double-buffered at 0 / 6144
#define XPLANE 2048
#define XBUF   (3 * XPLANE)

typedef __bf16 bf16x8 __attribute__((ext_vector_type(8)));
typedef float f32x4 __attribute__((ext_vector_type(4)));

// slot-major + XOR swizzle: conflict-free-ish writes, <=2-way reads
__device__ __forceinline__ int xslot(int token, int chunk) {
  return ((chunk * 32 + token) * 16) ^ ((token & 3) << 6);
}

// ---- f32 -> 3x bf16 split: x ~= hi + mid + lo (residuals Sterbenz-exact) ----
__device__ __forceinline__ void decomp8(const float v[8], uint4& H, uint4& M, uint4& L) {
  union U { __bf16 b[8]; uint4 u; } h, m, l;
#pragma unroll
  for (int i = 0; i < 8; ++i) {
    float xv = v[i];
    __bf16 hb = (__bf16)xv;
    float r1 = xv - (float)hb;
    __bf16 mb = (__bf16)r1;
    float r2 = r1 - (float)mb;
    h.b[i] = hb; m.b[i] = mb; l.b[i] = (__bf16)r2;
  }
  H = h.u; M = m.u; L = l.u;
}

// ================= pre-kernel: decompose w into frag-native ws layout ========
// ws block for (tile t, plane p, expert-block eb) = 1024 B at ((t*3+p)*16+eb)*1024.
// Within a block: lane = ((k&31)>>3)*16 + (e&15) holds 8 bf16 = w[e][t*32+(lane>>4)*8+j].
__global__ __launch_bounds__(256) void w_split_kernel(const float* __restrict__ wgt,
                                                      unsigned char* __restrict__ ws) {
  const int g = blockIdx.x * 256 + threadIdx.x;   // 131072 threads
  const int e = g >> 9;                            // expert 0..255
  const int k0 = (g & 511) << 3;                   // k chunk of 8
  const int kt = k0 >> 5;
  const int chunk = (k0 & 31) >> 3;
  const int lane = chunk * 16 + (e & 15);
  const int eb = e >> 4;
  float v[8];
  float4 a = *(const float4*)(wgt + (long)e * DIMK + k0);
  float4 b = *(const float4*)(wgt + (long)e * DIMK + k0 + 4);
  v[0]=a.x; v[1]=a.y; v[2]=a.z; v[3]=a.w; v[4]=b.x; v[5]=b.y; v[6]=b.z; v[7]=b.w;
  uint4 H, M, L;
  decomp8(v, H, M, L);
  const long base = ((long)(kt * 3) * 16 + eb) * 1024 + lane * 16;
  *(uint4*)(ws + base)             = H;   // p=0
  *(uint4*)(ws + base + 16 * 1024) = M;   // p=1
  *(uint4*)(ws + base + 32 * 1024) = L;   // p=2
}

// ================= helpers for the mfma main kernel ==========================
__device__ __forceinline__ void mfma_group(const bf16x8 a[2], const bf16x8* b, f32x4 D[2][4]) {
#pragma unroll
  for (int rt = 0; rt < 2; ++rt)
#pragma unroll
    for (int ct = 0; ct < 4; ++ct)
      D[rt][ct] = __builtin_amdgcn_mfma_f32_16x16x32_bf16(a[rt], b[ct], D[rt][ct], 0, 0, 0);
}

__device__ __forceinline__ void groups_for_tile(const unsigned char* smem, int bufoff,
                                                int l15, int chunk, const bf16x8* B,
                                                f32x4 D[2][4]) {
  bf16x8 ah[2], am[2], al[2];
#pragma unroll
  for (int rt = 0; rt < 2; ++rt) {
    const int off = xslot(rt * 16 + l15, chunk);
    ah[rt] = *(const bf16x8*)(smem + bufoff + 0 * XPLANE + off);
    am[rt] = *(const bf16x8*)(smem + bufoff + 1 * XPLANE + off);
    al[rt] = *(const bf16x8*)(smem + bufoff + 2 * XPLANE + off);
  }
  mfma_group(ah, B + 0, D);   // hi * w_hi
  mfma_group(am, B + 0, D);   // mid * w_hi
  mfma_group(al, B + 0, D);   // lo * w_hi
  mfma_group(ah, B + 4, D);   // hi * w_mid
  mfma_group(am, B + 4, D);   // mid * w_mid
  mfma_group(ah, B + 8, D);   // hi * w_lo
}

__device__ __forceinline__ void loadB(bf16x8* dst, const unsigned char* ws, int t,
                                      int wid, int lane) {
#pragma unroll
  for (int p = 0; p < 3; ++p)
#pragma unroll
    for (int ct = 0; ct < 4; ++ct)
      dst[p * 4 + ct] = *(const bf16x8*)(ws + ((long)((t * 3 + p) * 16 + wid * 4 + ct) << 10) + lane * 16);
}

// ================= main kernel: 32 tokens x 256 experts, bf16x3 MFMA =========
__global__ __launch_bounds__(256, 2) void moe_gate_mfma(
    const float* __restrict__ x, const unsigned char* __restrict__ ws,
    const float* __restrict__ bias, float* __restrict__ outw, float* __restrict__ outi) {
  // LDS: x-plane dbuf 12288 B (aliased), later sc[32][257] f64 = 65792 B total.
  __shared__ __align__(16) unsigned char smem[32 * 257 * 8];  // 65792 B -> 2 blocks/CU
  double* sc = (double*)smem;

  const int tid = threadIdx.x;
  const int wid = tid >> 6;
  const int lane = tid & 63;
  const int l15 = lane & 15;
  const int chunk = lane >> 4;   // k-chunk 0..3 for A-frag reads
  const long bm0 = (long)blockIdx.x * BM;

  // x staging: threads 0..127 cover 32 tokens x 4 chunks of 8 k
  const int token = (tid >> 2) & 31;
  const int part = tid & 3;
  const bool stager = (tid < 128);
  const float* xptr = x + (bm0 + token) * (long)DIMK + part * 8;
  const int xw = xslot(token, part);

  f32x4 D[2][4];
  double acc[2][4][4];
#pragma unroll
  for (int rt = 0; rt < 2; ++rt)
#pragma unroll
    for (int ct = 0; ct < 4; ++ct) {
      D[rt][ct] = (f32x4){0.f, 0.f, 0.f, 0.f};
#pragma unroll
      for (int r = 0; r < 4; ++r) acc[rt][ct][r] = 0.0;
    }

  bf16x8 bA[12], bB[12];
  uint4 XH, XM, XL;

  // ---- prologue: b-frags for tile 0; x tile 0 -> LDS buf0 ----
  loadB(bA, ws, 0, wid, lane);
  if (stager) {
    float v[8];
    float4 a0 = *(const float4*)(xptr);
    float4 a1 = *(const float4*)(xptr + 4);
    v[0]=a0.x; v[1]=a0.y; v[2]=a0.z; v[3]=a0.w; v[4]=a1.x; v[5]=a1.y; v[6]=a1.z; v[7]=a1.w;
    decomp8(v, XH, XM, XL);
    *(uint4*)(smem + 0 * XPLANE + xw) = XH;
    *(uint4*)(smem + 1 * XPLANE + xw) = XM;
    *(uint4*)(smem + 2 * XPLANE + xw) = XL;
  }
  __syncthreads();

#pragma unroll 1
  for (int it = 0; it < NT128 / 2; ++it) {
    const int t1 = 2 * it + 1;
    // ---------- tile t0 = 2*it : LDS buf0, b-frags in bA ----------
    loadB(bB, ws, t1, wid, lane);                     // prefetch next tile's w-frags
    if (stager) {
      float v[8];
      float4 a0 = *(const float4*)(xptr + t1 * BK32);
      float4 a1 = *(const float4*)(xptr + t1 * BK32 + 4);
      v[0]=a0.x; v[1]=a0.y; v[2]=a0.z; v[3]=a0.w; v[4]=a1.x; v[5]=a1.y; v[6]=a1.z; v[7]=a1.w;
      decomp8(v, XH, XM, XL);
    }
    groups_for_tile(smem, 0, l15, chunk, bA, D);
    if (stager) {
      *(uint4*)(smem + XBUF + 0 * XPLANE + xw) = XH;  // stage x(t1) -> buf1
      *(uint4*)(smem + XBUF + 1 * XPLANE + xw) = XM;
      *(uint4*)(smem + XBUF + 2 * XPLANE + xw) = XL;
    }
    __syncthreads();
    // ---------- tile t1 : LDS buf1, b-frags in bB ----------
    const bool more = (it + 1 < NT128 / 2);
    if (more) {
      loadB(bA, ws, t1 + 1, wid, lane);
      if (stager) {
        float v[8];
        float4 a0 = *(const float4*)(xptr + (t1 + 1) * BK32);
        float4 a1 = *(const float4*)(xptr + (t1 + 1) * BK32 + 4);
        v[0]=a0.x; v[1]=a0.y; v[2]=a0.z; v[3]=a0.w; v[4]=a1.x; v[5]=a1.y; v[6]=a1.z; v[7]=a1.w;
        decomp8(v, XH, XM, XL);
      }
    }
    groups_for_tile(smem, XBUF, l15, chunk, bB, D);
    if (more && stager) {
      *(uint4*)(smem + 0 * XPLANE + xw) = XH;         // stage x(t1+1) -> buf0
      *(uint4*)(smem + 1 * XPLANE + xw) = XM;
      *(uint4*)(smem + 2 * XPLANE + xw) = XL;
    }
    if ((it & 1) == 1) {                              // flush f32 -> f64 every 128 k
#pragma unroll
      for (int rt = 0; rt < 2; ++rt)
#pragma unroll
        for (int ct = 0; ct < 4; ++ct) {
#pragma unroll
          for (int r = 0; r < 4; ++r) acc[rt][ct][r] += (double)D[rt][ct][r];
          D[rt][ct] = (f32x4){0.f, 0.f, 0.f, 0.f};
        }
    }
    __syncthreads();
  }

  // ---- epilogue: f64 sigmoid + bias -> sc (aliases staging LDS) ----
#pragma unroll
  for (int rt = 0; rt < 2; ++rt)
#pragma unroll
    for (int ct = 0; ct < 4; ++ct) {
      const int col = wid * 64 + ct * 16 + l15;
      const double bd = (double)bias[col];
#pragma unroll
      for (int r = 0; r < 4; ++r) {
        const int row = rt * 16 + (lane >> 4) * 4 + r;
        const double s = 1.0 / (1.0 + exp(-acc[rt][ct][r]));  // original score
        sc[row * 257 + col] = s + bd;                         // biased, for ranking
      }
    }
  __syncthreads();

  // ---- routing: one lane per token (verbatim from the passing kernels) ----
  if (tid < BM) {
    double* row = sc + tid * 257;
    double gs[NGRP];
#pragma unroll
    for (int g = 0; g < NGRP; ++g) {
      double m1 = -1e300, m2 = -1e300;
      for (int e = 0; e < GSZ; ++e) {
        double v = row[g * GSZ + e];
        if (v > m1) { m2 = m1; m1 = v; }
        else if (v > m2) { m2 = v; }
      }
      gs[g] = m1 + m2;
    }
    unsigned msk = 0;
#pragma unroll
    for (int g = 0; g < NGRP; ++g) {
      int cnt = 0;
#pragma unroll
      for (int h = 0; h < NGRP; ++h)
        cnt += ((gs[h] > gs[g]) || (gs[h] == gs[g] && h > g)) ? 1 : 0;
      if (cnt < TOPKG) msk |= (1u << g);
    }
    int g0 = __ffs(msk) - 1; msk &= msk - 1;
    int g1 = __ffs(msk) - 1; msk &= msk - 1;
    int g2 = __ffs(msk) - 1; msk &= msk - 1;
    int g3 = __ffs(msk) - 1;

    double wv[TOPKE];
    float iv[TOPKE];
#pragma unroll
    for (int r8 = 0; r8 < TOPKE; ++r8) {
      double best = -1e300;
      int bi = 0;
      {
        int gg = g0;
        for (int e = 0; e < GSZ; ++e) { double v = row[gg * GSZ + e]; if (v >= best) { best = v; bi = gg * GSZ + e; } }
        gg = g1;
        for (int e = 0; e < GSZ; ++e) { double v = row[gg * GSZ + e]; if (v >= best) { best = v; bi = gg * GSZ + e; } }
        gg = g2;
        for (int e = 0; e < GSZ; ++e) { double v = row[gg * GSZ + e]; if (v >= best) { best = v; bi = gg * GSZ + e; } }
        gg = g3;
        for (int e = 0; e < GSZ; ++e) { double v = row[gg * GSZ + e]; if (v >= best) { best = v; bi = gg * GSZ + e; } }
      }
      row[bi] = -1e300;
      wv[7 - r8] = best - (double)bias[bi];
      iv[7 - r8] = (float)bi;
    }
    double sum = 0.0;
#pragma unroll
    for (int p = 0; p < TOPKE; ++p) sum += wv[p];
    const double den = sum + 1e-20;
    const long trow = bm0 + tid;
#pragma unroll
    for (int p = 0; p < TOPKE; ++p) {
      outw[trow * 8 + p] = (float)(wv[p] / den * 2.5);
      outi[trow * 8 + p] = iv[p];
    }
  }
}

// ================= fallback: round-2 f64-VALU kernel (known-PASS) ============
#define BMF  64
#define BKF 16
#define LXSF 68
__global__ __launch_bounds__(256, 1) void moe_gate_f64(
    const float* __restrict__ x, const float* __restrict__ wgt,
    const float* __restrict__ bias, float* __restrict__ outw,
    float* __restrict__ outi) {
  __shared__ __align__(16) unsigned char smem[64 * 257 * 8];
  float* lw = (float*)smem;
  float* lx = (float*)(smem + 32768);
  double* sc = (double*)smem;
  const int tid = threadIdx.x;
  const long bm0 = (long)blockIdx.x * BMF;
  const int rg = tid >> 5;
  const int cg = tid & 31;
  const int sxr = tid >> 2;
  const int sxj = (tid & 3) << 2;
  const float* xrow = x + (bm0 + sxr) * (long)DIMK + sxj;
  const float* wrow = wgt + (long)tid * DIMK;
  double acc[8][8];
#pragma unroll
  for (int i = 0; i < 8; ++i)
#pragma unroll
    for (int j = 0; j < 8; ++j) acc[i][j] = 0.0;
#define LWF(b, k, e) lw[((b)*BKF + (k)) * NEXP + (e)]
#define LXF(b, k, r) lx[((b)*BKF + (k)) * LXSF + (r)]
  {
    float4 xv = *(const float4*)(xrow);
#pragma unroll
    for (int c = 0; c < 4; ++c) LXF(0, sxj + c, sxr) = ((const float*)&xv)[c];
#pragma unroll
    for (int jj = 0; jj < 4; ++jj) {
      float4 wv = *(const float4*)(wrow + jj * 4);
#pragma unroll
      for (int c = 0; c < 4; ++c) LWF(0, jj * 4 + c, tid) = ((const float*)&wv)[c];
    }
  }
  __syncthreads();
  const int NTF = DIMK / BKF;
  for (int kt = 0; kt < NTF; ++kt) {
    const int b = kt & 1;
    if (kt + 1 < NTF) {
      const int k0 = (kt + 1) * BKF;
      const int nb = b ^ 1;
      float4 xv = *(const float4*)(xrow + k0);
      float4 wv0 = *(const float4*)(wrow + k0);
      float4 wv1 = *(const float4*)(wrow + k0 + 4);
      float4 wv2 = *(const float4*)(wrow + k0 + 8);
      float4 wv3 = *(const float4*)(wrow + k0 + 12);
#pragma unroll
      for (int c = 0; c < 4; ++c) LXF(nb, sxj + c, sxr) = ((const float*)&xv)[c];
#pragma unroll
      for (int c = 0; c < 4; ++c) LWF(nb, 0 + c, tid) = ((const float*)&wv0)[c];
#pragma unroll
      for (int c = 0; c < 4; ++c) LWF(nb, 4 + c, tid) = ((const float*)&wv1)[c];
#pragma unroll
      for (int c = 0; c < 4; ++c) LWF(nb, 8 + c, tid) = ((const float*)&wv2)[c];
#pragma unroll
      for (int c = 0; c < 4; ++c) LWF(nb, 12 + c, tid) = ((const float*)&wv3)[c];
    }
#pragma unroll
    for (int k = 0; k < BKF; ++k) {
      float4 a0 = *(const float4*)(&LXF(b, k, rg * 8));
      float4 a1 = *(const float4*)(&LXF(b, k, rg * 8 + 4));
      double ad[8] = {(double)a0.x, (double)a0.y, (double)a0.z, (double)a0.w,
                      (double)a1.x, (double)a1.y, (double)a1.z, (double)a1.w};
      double bd[8];
#pragma unroll
      for (int j = 0; j < 4; ++j) {
        float2 bb = *(const float2*)(&LWF(b, k, cg * 2 + 64 * j));
        bd[2 * j] = (double)bb.x;
        bd[2 * j + 1] = (double)bb.y;
      }
#pragma unroll
      for (int i = 0; i < 8; ++i)
#pragma unroll
        for (int j = 0; j < 8; ++j) acc[i][j] += ad[i] * bd[j];
    }
    __syncthreads();
  }
  double bc[8];
#pragma unroll
  for (int j = 0; j < 4; ++j) {
    bc[2 * j] = (double)bias[cg * 2 + 64 * j];
    bc[2 * j + 1] = (double)bias[cg * 2 + 64 * j + 1];
  }
#pragma unroll
  for (int i = 0; i < 8; ++i) {
    const int r = rg * 8 + i;
#pragma unroll
    for (int jq = 0; jq < 8; ++jq) {
      const int col = cg * 2 + 64 * (jq >> 1) + (jq & 1);
      double s = 1.0 / (1.0 + exp(-acc[i][jq]));
      sc[r * 257 + col] = s + bc[jq];
    }
  }
  __syncthreads();
  if (tid < BMF) {
    double* row = sc + tid * 257;
    double gs[NGRP];
#pragma unroll
    for (int g = 0; g < NGRP; ++g) {
      double m1 = -1e300, m2 = -1e300;
      for (int e = 0; e < GSZ; ++e) {
        double v = row[g * GSZ + e];
        if (v > m1) { m2 = m1; m1 = v; }
        else if (v > m2) { m2 = v; }
      }
      gs[g] = m1 + m2;
    }
    unsigned msk = 0;
#pragma unroll
    for (int g = 0; g < NGRP; ++g) {
      int cnt = 0;
#pragma unroll
      for (int h = 0; h < NGRP; ++h)
        cnt += ((gs[h] > gs[g]) || (gs[h] == gs[g] && h > g)) ? 1 : 0;
      if (cnt < TOPKG) msk |= (1u << g);
    }
    int g0 = __ffs(msk) - 1; msk &= msk - 1;
    int g1 = __ffs(msk) - 1; msk &= msk - 1;
    int g2 = __ffs(msk) - 1; msk &= msk - 1;
    int g3 = __ffs(msk) - 1;
    double wv[TOPKE];
    float iv[TOPKE];
#pragma unroll
    for (int r8 = 0; r8 < TOPKE; ++r8) {
      double best = -1e300;
      int bi = 0;
      {
        int gg = g0;
        for (int e = 0; e < GSZ; ++e) { double v = row[gg * GSZ + e]; if (v >= best) { best = v; bi = gg * GSZ + e; } }
        gg = g1;
        for (int e = 0; e < GSZ; ++e) { double v = row[gg * GSZ + e]; if (v >= best) { best = v; bi = gg * GSZ + e; } }
        gg = g2;
        for (int e = 0; e < GSZ; ++e) { double v = row[gg * GSZ + e]; if (v >= best) { best = v; bi = gg * GSZ + e; } }
        gg = g3;
        for (int e = 0; e < GSZ; ++e) { double v = row[gg * GSZ + e]; if (v >= best) { best = v; bi = gg * GSZ + e; } }
      }
      row[bi] = -1e300;
      wv[7 - r8] = best - (double)bias[bi];
      iv[7 - r8] = (float)bi;
    }
    double sum = 0.0;
#pragma unroll
    for (int p = 0; p < TOPKE; ++p) sum += wv[p];
    const double den = sum + 1e-20;
    const long trow = bm0 + tid;
#pragma unroll
    for (int p = 0; p < TOPKE; ++p) {
      outw[trow * 8 + p] = (float)(wv[p] / den * 2.5);
      outi[trow * 8 + p] = iv[p];
    }
  }
}

extern "C" void kernel_launch(void* const* d_in, const int* in_sizes, int n_in,
                              void* d_out, int out_size, void* d_ws, size_t ws_size,
                              hipStream_t stream) {
  const float* x = (const float*)d_in[0];
  const float* w = (const float*)d_in[1];
  const float* b = (const float*)d_in[2];
  const int ntok = in_sizes[0] / DIMK;  // 16384
  float* outw = (float*)d_out;
  float* outi = outw + (size_t)ntok * 8;
  if (ws_size >= WS_NEED) {
    hipLaunchKernelGGL(w_split_kernel, dim3(512), dim3(256), 0, stream,
                       w, (unsigned char*)d_ws);
    hipLaunchKernelGGL(moe_gate_mfma, dim3(ntok / BM), dim3(256), 0, stream,
                       x, (const unsigned char*)d_ws, b, outw, outi);
  } else {
    hipLaunchKernelGGL(moe_gate_f64, dim3(ntok / 64), dim3(256), 0, stream,
                       x, w, b, outw, outi);
  }
}